// Round 9
// baseline (169.550 us; speedup 1.0000x reference)
//
#include <hip/hip_runtime.h>

#define B_  8
#define TQ  128
#define TV  128
#define DIM 512
#define UU  1024
#define C2  2.885390081777927f   // 2*log2(e)

typedef __attribute__((ext_vector_type(8))) short     short8;   // 8 bf16 (4 VGPRs)
typedef __attribute__((ext_vector_type(4))) float     f32x4;
typedef __attribute__((ext_vector_type(2))) float     f32x2;    // packed-f32 pair
typedef __attribute__((ext_vector_type(4))) unsigned short us4;

__device__ __forceinline__ unsigned short bf16_rtne(float x) {
    unsigned u = __float_as_uint(x);
    unsigned r = u + 0x7FFF + ((u >> 16) & 1);
    return (unsigned short)(r >> 16);
}

__device__ __forceinline__ us4 cvt4(float4 v) {
    us4 h;
    h.x = bf16_rtne(v.x);
    h.y = bf16_rtne(v.y);
    h.z = bf16_rtne(v.z);
    h.w = bf16_rtne(v.w);
    return h;
}

__device__ __forceinline__ f32x2 pkfma(f32x2 a, f32x2 b, f32x2 c) {
    return __builtin_elementwise_fma(a, b, c);
}

// ---------------------------------------------------------------------------
// Kernel 1: dual bf16 GEMM + exp2 epilogue, prep fused into staging.
// Ek written TRANSPOSED as EkT[b][u][s] so k_sac's stage loads are linear.
// The scattered epilogue (16 lines/store) runs ONCE (~0.3us); it replaces
// k_sac's per-chunk 64-line stage loads (8x tag traffic).  Eq unchanged.
// (R8 source resubmitted verbatim: R8 bench was an infra failure, not a
// kernel verdict; source re-audited for bounds/barriers/alignment.)
// ---------------------------------------------------------------------------
#define PKP 72   // shorts pitch: 144 B
__global__ __launch_bounds__(256, 2) void k_proj(
    const float* __restrict__ Q, const float* __restrict__ Vv,
    const float* __restrict__ W1, const float* __restrict__ W2,
    float* __restrict__ Eq, float* __restrict__ EkT)
{
    __shared__ short sAb[64 * PKP], sBh[64 * PKP];

    const int tid  = threadIdx.x;
    const int wave = tid >> 6;
    const int lane = tid & 63;

    const int flat = blockIdx.x;
    const int x    = flat & 7;
    const int j    = flat >> 3;
    const int pair = x * 4 + (j >> 4);   // 0..31
    const int nt   = pair & 15;
    const int mat  = pair >> 4;
    const int mt   = j & 15;
    const int m0   = mt * 64;
    const int n0   = nt * 64;

    const float* Asrc = mat ? Vv : Q;    // [row][k]
    const float* Wsrc = mat ? W2 : W1;   // [k][n]

    const int wm = (wave & 1) * 32;
    const int wn = (wave >> 1) * 32;

    const int sm = tid >> 2, sg = tid & 3;
    const float* gA = Asrc + (m0 + sm) * 512;
    const int so0 = sm * PKP + sg * 8;
    const int so1 = sm * PKP + 32 + sg * 8;

    const int kk = tid & 63, ng = tid >> 6;
    const float* gW = Wsrc + n0 + ng * 16;

    const int fr = lane & 15, fq = lane >> 4;
    const int aOff0 = (wm + fr) * PKP + fq * 8;
    const int aOff1 = (wm + 16 + fr) * PKP + fq * 8;
    const int bOff0 = (wn + fr) * PKP + fq * 8;
    const int bOff1 = (wn + 16 + fr) * PKP + fq * 8;

    f32x4 acc00 = {0.f, 0.f, 0.f, 0.f};
    f32x4 acc01 = {0.f, 0.f, 0.f, 0.f};
    f32x4 acc10 = {0.f, 0.f, 0.f, 0.f};
    f32x4 acc11 = {0.f, 0.f, 0.f, 0.f};

    float4 a0, a1, a2, a3, w0, w1, w2, w3;
    #define LOADALL(K)                                                       \
        a0 = *(const float4*)(gA + (K) + sg * 8);                            \
        a1 = *(const float4*)(gA + (K) + sg * 8 + 4);                        \
        a2 = *(const float4*)(gA + (K) + 32 + sg * 8);                       \
        a3 = *(const float4*)(gA + (K) + 32 + sg * 8 + 4);                   \
        {                                                                    \
            const float* wr = gW + ((K) + kk) * UU;                          \
            w0 = *(const float4*)(wr);                                       \
            w1 = *(const float4*)(wr + 4);                                   \
            w2 = *(const float4*)(wr + 8);                                   \
            w3 = *(const float4*)(wr + 12);                                  \
        }

    LOADALL(0)

    #pragma unroll 1
    for (int kc = 0; kc < 8; ++kc) {
        *(us4*)&sAb[so0]     = cvt4(a0);
        *(us4*)&sAb[so0 + 4] = cvt4(a1);
        *(us4*)&sAb[so1]     = cvt4(a2);
        *(us4*)&sAb[so1 + 4] = cvt4(a3);
        {
            us4 h[4] = {cvt4(w0), cvt4(w1), cvt4(w2), cvt4(w3)};
            #pragma unroll
            for (int g = 0; g < 4; ++g) {
                sBh[(ng * 16 + g * 4 + 0) * PKP + kk] = (short)h[g].x;
                sBh[(ng * 16 + g * 4 + 1) * PKP + kk] = (short)h[g].y;
                sBh[(ng * 16 + g * 4 + 2) * PKP + kk] = (short)h[g].z;
                sBh[(ng * 16 + g * 4 + 3) * PKP + kk] = (short)h[g].w;
            }
        }
        __syncthreads();

        if (kc < 7) { LOADALL((kc + 1) * 64) }

        #pragma unroll
        for (int ks = 0; ks < 2; ++ks) {
            const int o = ks * 32;
            short8 fa0 = *(const short8*)&sAb[aOff0 + o];
            short8 fa1 = *(const short8*)&sAb[aOff1 + o];
            short8 fb0 = *(const short8*)&sBh[bOff0 + o];
            short8 fb1 = *(const short8*)&sBh[bOff1 + o];

            acc00 = __builtin_amdgcn_mfma_f32_16x16x32_bf16(fa0, fb0, acc00, 0, 0, 0);
            acc01 = __builtin_amdgcn_mfma_f32_16x16x32_bf16(fa0, fb1, acc01, 0, 0, 0);
            acc10 = __builtin_amdgcn_mfma_f32_16x16x32_bf16(fa1, fb0, acc10, 0, 0, 0);
            acc11 = __builtin_amdgcn_mfma_f32_16x16x32_bf16(fa1, fb1, acc11, 0, 0, 0);
        }
        __syncthreads();
    }
    #undef LOADALL

    if (mat) {
        // EkT[b][u][s]: offset = (bb*UU + u)*TV + s
        // bb = m0>>7 valid: rows [m0+wm, m0+wm+31] never cross a 128-batch
        // boundary (m0 mod 128 in {0,64}, wm <= 32).
        const int bb = m0 >> 7;
        #pragma unroll
        for (int r = 0; r < 4; ++r) {
            int row0 = m0 + wm + fq * 4 + r;
            int row1 = row0 + 16;
            int s0_  = row0 & 127, s1_ = row1 & 127;
            int col0 = n0 + wn + fr;
            EkT[(bb * UU + col0) * TV + s0_]      = __builtin_amdgcn_exp2f(C2 * acc00[r]);
            EkT[(bb * UU + col0 + 16) * TV + s0_] = __builtin_amdgcn_exp2f(C2 * acc01[r]);
            EkT[(bb * UU + col0) * TV + s1_]      = __builtin_amdgcn_exp2f(C2 * acc10[r]);
            EkT[(bb * UU + col0 + 16) * TV + s1_] = __builtin_amdgcn_exp2f(C2 * acc11[r]);
        }
    } else {
        #pragma unroll
        for (int r = 0; r < 4; ++r) {
            int row0 = m0 + wm + fq * 4 + r;
            int row1 = row0 + 16;
            int col0 = n0 + wn + fr;
            Eq[row0 * UU + col0]      = __builtin_amdgcn_exp2f(C2 * acc00[r]);
            Eq[row0 * UU + col0 + 16] = __builtin_amdgcn_exp2f(C2 * acc01[r]);
            Eq[row1 * UU + col0]      = __builtin_amdgcn_exp2f(C2 * acc10[r]);
            Eq[row1 * UU + col0 + 16] = __builtin_amdgcn_exp2f(C2 * acc11[r]);
        }
    }
}
#undef PKP

// ---------------------------------------------------------------------------
// Kernel 2 v3: fused scores -> softmax -> attn,ctx.
// R7 post-mortem: insensitive to TLP/ILP -> bound by uncoalesced stage loads
// (8KB lane stride = 64 lines/wave-load, ~65K tag transactions/CU).
// v3: EkT[b][u][s] layout -> stage reads a CONTIGUOUS 32KB block per chunk
// (8x less tag traffic); double-buffered register prefetch (rA/rB, static)
// hides L2 latency under compute; Q/scale staged once.  Compute math and
// u-order identical to R7 -> scores bitwise identical.
// ---------------------------------------------------------------------------
#define ETP 132   // ekT row pitch (floats): 16B-aligned rows, 2-way max alias
__global__ __launch_bounds__(256, 2) void k_sac(
    const float* __restrict__ Eq, const float* __restrict__ EkT,
    const float* __restrict__ scale, const int* __restrict__ mask,
    const float* __restrict__ Vv,
    float* __restrict__ attn, float* __restrict__ ctx)
{
    __shared__ float ekT[64][ETP];     // [u][s]  33.8 KB
    __shared__ float qs_all[2][1024];  // 8 KB
    __shared__ float ss_all[1024];     // 4 KB
    __shared__ float at[2][132];
    __shared__ f32x2 pacc[2][2][64];   // [row][u-half][s-pair]

    const int tid = threadIdx.x;
    const int bid = blockIdx.x;
    const int b   = bid & 7;         // XCD-affine: EkT[b] in one L2
    const int t0  = (bid >> 3) * 2;  // 2 q-rows per block
    const int sp  = tid & 63;        // s-pair: s = 2sp, 2sp+1
    const int rw  = tid >> 7;        // q-row (uniform per wave)
    const int uh  = (tid >> 6) & 1;  // u-half of chunk (uniform per wave)

    // ---- one-time stage: Q rows + scale (3 f4 per thread, coalesced) ----
    {
        #pragma unroll
        for (int i = 0; i < 3; ++i) {
            int fidx = i * 256 + tid;          // 0..767 f4-index
            if (fidx < 512) {
                int rr = fidx >> 8, c4 = fidx & 255;
                *(float4*)&qs_all[rr][c4 * 4] =
                    *(const float4*)&Eq[(b * TQ + t0 + rr) * UU + c4 * 4];
            } else {
                int c4 = fidx - 512;
                *(float4*)&ss_all[c4 * 4] = *(const float4*)&scale[c4 * 4];
            }
        }
    }

    const float* ekg = &EkT[(size_t)b * UU * TV];

    float4 rA[8], rB[8];
    #define LOADC(UC, R)                                                     \
        {   const int u0_ = (UC) * 64;                                       \
            _Pragma("unroll")                                                \
            for (int i = 0; i < 8; ++i) {                                    \
                int fidx = i * 256 + tid;                                    \
                int ul = fidx >> 5, cc = fidx & 31;                          \
                R[i] = *(const float4*)&ekg[(u0_ + ul) * TV + cc * 4];       \
            }                                                                \
        }
    #define WRITEC(R)                                                       \
        {   _Pragma("unroll")                                                \
            for (int i = 0; i < 8; ++i) {                                    \
                int fidx = i * 256 + tid;                                    \
                int ul = fidx >> 5, cc = fidx & 31;                          \
                *(float4*)&ekT[ul][cc * 4] = R[i];                           \
            }                                                                \
        }

    f32x2 acc0 = {0.f, 0.f}, acc1 = {0.f, 0.f};
    const f32x2 one2 = {1.f, 1.f};

    #define COMPUTE(UC)                                                      \
        {   _Pragma("unroll")                                                \
            for (int u4 = 0; u4 < 8; ++u4) {                                 \
                const int g = uh * 8 + u4;                                   \
                f32x2 kA0 = *(const f32x2*)&ekT[g * 4 + 0][2 * sp];          \
                f32x2 kA1 = *(const f32x2*)&ekT[g * 4 + 1][2 * sp];          \
                f32x2 kA2 = *(const f32x2*)&ekT[g * 4 + 2][2 * sp];          \
                f32x2 kA3 = *(const f32x2*)&ekT[g * 4 + 3][2 * sp];          \
                float4 qv = *(const float4*)&qs_all[rw][(UC) * 64 + g * 4];  \
                float4 sv = *(const float4*)&ss_all[(UC) * 64 + g * 4];      \
                f32x2 b1 = pkfma((f32x2){qv.x, qv.x}, kA0, one2);            \
                f32x2 b2 = pkfma((f32x2){qv.y, qv.y}, kA1, one2);            \
                f32x2 p  = b1 * b2;                                          \
                f32x2 n  = pkfma((f32x2){sv.y, sv.y}, b1,                    \
                                 (f32x2){sv.x, sv.x} * b2);                  \
                f32x2 rc = {__builtin_amdgcn_rcpf(p.x),                      \
                            __builtin_amdgcn_rcpf(p.y)};                     \
                acc0 = pkfma(n, rc, acc0);                                   \
                f32x2 b3 = pkfma((f32x2){qv.z, qv.z}, kA2, one2);            \
                f32x2 b4 = pkfma((f32x2){qv.w, qv.w}, kA3, one2);            \
                f32x2 p2 = b3 * b4;                                          \
                f32x2 n2 = pkfma((f32x2){sv.w, sv.w}, b3,                    \
                                 (f32x2){sv.z, sv.z} * b4);                  \
                f32x2 rc2 = {__builtin_amdgcn_rcpf(p2.x),                    \
                             __builtin_amdgcn_rcpf(p2.y)};                   \
                acc1 = pkfma(n2, rc2, acc1);                                 \
            }                                                                \
        }

    LOADC(0, rA)

    #pragma unroll 1
    for (int uc2 = 0; uc2 < 8; ++uc2) {
        const int ucA = uc2 * 2, ucB = uc2 * 2 + 1;
        if (uc2) __syncthreads();      // prev compute done reading ekT
        WRITEC(rA)
        LOADC(ucB, rB)                 // lands under COMPUTE(ucA)
        __syncthreads();
        COMPUTE(ucA)
        __syncthreads();
        WRITEC(rB)
        if (uc2 < 7) LOADC(ucA + 2, rA)
        __syncthreads();
        COMPUTE(ucB)
    }
    #undef LOADC
    #undef WRITEC
    #undef COMPUTE

    pacc[rw][uh][sp] = acc0 + acc1;
    __syncthreads();

    // ---- softmax: waves 0,1 -> rows 0,1 ----
    if (tid < 128) {
        const int rr  = tid >> 6;
        const int sp2 = tid & 63;
        f32x2 pa = pacc[rr][0][sp2];
        f32x2 pb = pacc[rr][1][sp2];
        f32x2 acc = {pa.x + pb.x, pa.y + pb.y};

        const int2 mk = *(const int2*)&mask[b * TV + 2 * sp2];
        float x0 = mk.x ? -2.f * acc.x : -1e9f;
        float x1 = mk.y ? -2.f * acc.y : -1e9f;
        float m = fmaxf(x0, x1);
        #pragma unroll
        for (int o = 32; o > 0; o >>= 1) m = fmaxf(m, __shfl_xor(m, o, 64));
        const float L2E = 1.4426950408889634f;
        float e0 = __builtin_amdgcn_exp2f((x0 - m) * L2E);
        float e1 = __builtin_amdgcn_exp2f((x1 - m) * L2E);
        float sum = e0 + e1;
        #pragma unroll
        for (int o = 32; o > 0; o >>= 1) sum += __shfl_xor(sum, o, 64);
        const float rs = __builtin_amdgcn_rcpf(sum);
        const float av0 = e0 * rs, av1 = e1 * rs;

        *(float2*)&attn[(b * TQ + t0 + rr) * TV + 2 * sp2] =
            (float2){av0, av1};
        at[rr][2 * sp2]     = av0;
        at[rr][2 * sp2 + 1] = av1;
    }
    __syncthreads();

    // ---- PV: thread (pr = tid>>7, 4 d); V reads fully coalesced ----
    const int pr = tid >> 7;
    const int dl = (tid & 127) * 4;
    float c0 = 0.f, c1 = 0.f, c2 = 0.f, c3 = 0.f;
    const float* vp = &Vv[b * TV * DIM + dl];
    #pragma unroll 4
    for (int s = 0; s < TV; ++s) {
        float a  = at[pr][s];                       // LDS broadcast
        float4 v = *(const float4*)(vp + s * DIM);
        c0 = fmaf(a, v.x, c0); c1 = fmaf(a, v.y, c1);
        c2 = fmaf(a, v.z, c2); c3 = fmaf(a, v.w, c3);
    }
    *(float4*)&ctx[(b * TQ + t0 + pr) * DIM + dl] = (float4){c0, c1, c2, c3};
}
#undef ETP

// ---------------------------------------------------------------------------
extern "C" void kernel_launch(void* const* d_in, const int* in_sizes, int n_in,
                              void* d_out, int out_size, void* d_ws, size_t ws_size,
                              hipStream_t stream)
{
    const float* query = (const float*)d_in[0];
    const float* value = (const float*)d_in[1];
    const int*   mask  = (const int*)d_in[2];
    const float* W1    = (const float*)d_in[3];
    const float* W2    = (const float*)d_in[4];
    const float* scale = (const float*)d_in[5];

    float* out  = (float*)d_out;
    float* ctx  = out;                    // [B, Tq, D]
    float* attn = out + B_ * TQ * DIM;    // [B, Tq, Tv]

    float* Eq  = (float*)d_ws;            // 4 MB
    float* EkT = Eq + 1024 * 1024;        // 4 MB, [B][U][S]

    hipLaunchKernelGGL(k_proj, dim3(512), dim3(256), 0, stream,
                       query, value, W1, W2, Eq, EkT);
    hipLaunchKernelGGL(k_sac,  dim3(512), dim3(256), 0, stream,
                       Eq, EkT, scale, mask, value, attn, ctx);
}